// Round 1
// baseline (330.951 us; speedup 1.0000x reference)
//
#include <hip/hip_runtime.h>
#include <math.h>

typedef __attribute__((ext_vector_type(8))) short bf16x8;
typedef __attribute__((ext_vector_type(4))) float f32x4;
typedef __attribute__((ext_vector_type(16))) float f32x16;

__device__ inline short f2bf(float f) {
  unsigned u = __builtin_bit_cast(unsigned, f);
  u = u + 0x7fffu + ((u >> 16) & 1u);
  return (short)(u >> 16);
}

// ---------------- weight transpose fp32[K,N] -> bf16[N,K] ----------------
__global__ __launch_bounds__(256) void wtrans_kernel(
    const float* __restrict__ in, short* __restrict__ out, int K, int N) {
  __shared__ float tile[32][33];
  const int tx = threadIdx.x & 31, ty = threadIdx.x >> 5;
  const int n0 = blockIdx.x * 32, k0 = blockIdx.y * 32;
  #pragma unroll
  for (int r = ty; r < 32; r += 8)
    tile[r][tx] = in[(size_t)(k0 + r) * N + n0 + tx];
  __syncthreads();
  #pragma unroll
  for (int r = ty; r < 32; r += 8)
    out[(size_t)(n0 + r) * K + k0 + tx] = f2bf(tile[tx][r]);
}

// ---------------- sinusoidal rpe table -> bf16 [2047][64] ----------------
__global__ __launch_bounds__(256) void rpe_kernel(short* __restrict__ tbl) {
  const int idx = blockIdx.x * 256 + threadIdx.x;
  if (idx >= 2047 * 64) return;
  const int row = idx >> 6, c = idx & 63;
  const float dist = (float)(row - 1023);
  const float inv = powf(10000.0f, -(float)(c & 31) * (1.0f / 32.0f));
  const float f = dist * inv;
  tbl[idx] = f2bf((c < 32) ? sinf(f) : cosf(f));
}

// ---------------- LayerNorm fp32 row(768) -> bf16 ----------------
__global__ __launch_bounds__(256) void ln_kernel(
    const float* __restrict__ x, const float* __restrict__ w,
    short* __restrict__ out) {
  const int row = blockIdx.x, tid = threadIdx.x;
  const float* xr = x + (size_t)row * 768;
  float v0 = xr[tid], v1 = xr[tid + 256], v2 = xr[tid + 512];
  float s = v0 + v1 + v2;
  #pragma unroll
  for (int o = 1; o < 64; o <<= 1) s += __shfl_xor(s, o);
  __shared__ float red[8];
  const int wv = tid >> 6;
  if ((tid & 63) == 0) red[wv] = s;
  __syncthreads();
  const float mean = (red[0] + red[1] + red[2] + red[3]) * (1.0f / 768.0f);
  v0 -= mean; v1 -= mean; v2 -= mean;
  float q = v0 * v0 + v1 * v1 + v2 * v2;
  #pragma unroll
  for (int o = 1; o < 64; o <<= 1) q += __shfl_xor(q, o);
  if ((tid & 63) == 0) red[4 + wv] = q;
  __syncthreads();
  const float var = (red[4] + red[5] + red[6] + red[7]) * (1.0f / 768.0f);
  const float inv = 1.0f / sqrtf(var + 1e-5f);
  out[(size_t)row * 768 + tid]       = f2bf(v0 * inv * w[tid]);
  out[(size_t)row * 768 + tid + 256] = f2bf(v1 * inv * w[tid + 256]);
  out[(size_t)row * 768 + tid + 512] = f2bf(v2 * inv * w[tid + 512]);
}

// ---------------- V transpose: qkv v-part -> vT[b,h,d,t] ----------------
__global__ __launch_bounds__(256) void vtrans_kernel(
    const short* __restrict__ qkv, short* __restrict__ vT) {
  __shared__ short tile[64][65];
  const int blk = blockIdx.x;
  const int bh = blk >> 4, t0 = (blk & 15) * 64;
  const int b = bh / 12, h = bh % 12;
  const int tx = threadIdx.x & 63, ty = threadIdx.x >> 6;
  const short* src = qkv + (size_t)(b * 1024 + t0) * 2304 + 1536 + h * 64;
  #pragma unroll
  for (int r = ty; r < 64; r += 4)
    tile[r][tx] = src[(size_t)r * 2304 + tx];
  __syncthreads();
  short* dst = vT + (size_t)bh * 64 * 1024 + t0;
  #pragma unroll
  for (int r = ty; r < 64; r += 4)
    dst[(size_t)r * 1024 + tx] = tile[tx][r];
}

// ---------------- GEMM: C[M,N] = A[M,K](bf16) x Bt[N,K](bf16) ----------------
// EPI 0: store bf16   EPI 1: fp32 out = res + acc   EPI 2: bf16 gelu(acc)
template <int EPI>
__global__ __launch_bounds__(256) void gemm_bt(
    const short* __restrict__ A, const short* __restrict__ Bt,
    const float* __restrict__ res, float* __restrict__ outF,
    short* __restrict__ outB, int M, int N, int K) {
  __shared__ short As[128 * 40];
  __shared__ short Bs[128 * 40];
  const int tid = threadIdx.x;
  const int w = tid >> 6, lane = tid & 63;
  const int m0 = blockIdx.y * 128, n0 = blockIdx.x * 128;
  const int wm = (w >> 1) * 64, wn = (w & 1) * 64;
  f32x4 acc[4][4];
  #pragma unroll
  for (int i = 0; i < 4; i++)
    #pragma unroll
    for (int j = 0; j < 4; j++)
      #pragma unroll
      for (int r = 0; r < 4; r++) acc[i][j][r] = 0.0f;

  for (int kt = 0; kt < K; kt += 32) {
    __syncthreads();
    #pragma unroll
    for (int p = 0; p < 2; ++p) {
      const int li16 = p * 256 + tid;
      const int row = li16 >> 2;
      const int kp = (li16 & 3) * 8;
      *(int4*)&As[row * 40 + kp] =
          *(const int4*)(A + (size_t)(m0 + row) * K + kt + kp);
      *(int4*)&Bs[row * 40 + kp] =
          *(const int4*)(Bt + (size_t)(n0 + row) * K + kt + kp);
    }
    __syncthreads();
    bf16x8 af[4], bfr[4];
    #pragma unroll
    for (int i = 0; i < 4; i++) {
      af[i]  = *(const bf16x8*)&As[(wm + i * 16 + (lane & 15)) * 40 + (lane >> 4) * 8];
      bfr[i] = *(const bf16x8*)&Bs[(wn + i * 16 + (lane & 15)) * 40 + (lane >> 4) * 8];
    }
    #pragma unroll
    for (int i = 0; i < 4; i++)
      #pragma unroll
      for (int j = 0; j < 4; j++)
        acc[i][j] = __builtin_amdgcn_mfma_f32_16x16x32_bf16(af[i], bfr[j],
                                                            acc[i][j], 0, 0, 0);
  }
  const int r0 = (lane >> 4) * 4, cl = lane & 15;
  #pragma unroll
  for (int i = 0; i < 4; i++) {
    #pragma unroll
    for (int j = 0; j < 4; j++) {
      const int gm = m0 + wm + i * 16 + r0;
      const int gn = n0 + wn + j * 16 + cl;
      #pragma unroll
      for (int r = 0; r < 4; r++) {
        const size_t idx = (size_t)(gm + r) * N + gn;
        const float v = acc[i][j][r];
        if constexpr (EPI == 0) {
          outB[idx] = f2bf(v);
        } else if constexpr (EPI == 1) {
          outF[idx] = res[idx] + v;
        } else {
          outB[idx] = f2bf(0.5f * v * (1.0f + erff(v * 0.70710678118f)));
        }
      }
    }
  }
}

// ---------------- fused causal attention with relative-pos term ----------------
// 1 wave per block; block = (b, h, 32-row query tile). Swapped-operand MFMA:
// S^T = mfma(K, Q) so lane owns one query row (col = lane&31).
__global__ __launch_bounds__(64) void attn_kernel(
    const short* __restrict__ qkv, const short* __restrict__ vT,
    const short* __restrict__ tbl, short* __restrict__ yout) {
  __shared__ float G[32 * 65];
  __shared__ float fl[32];
  __shared__ short P[32 * 40];
  const int blk = blockIdx.x;
  const int it = blk & 31, bh = blk >> 5;
  const int b = bh / 12, h = bh % 12;
  const int I0 = it * 32;
  const int lane = threadIdx.x;
  const int li = lane & 31, hi = lane >> 5;

  const short* qrow = qkv + (size_t)(b * 1024 + I0 + li) * 2304 + h * 64;
  bf16x8 qf[4];
  #pragma unroll
  for (int s = 0; s < 4; s++) qf[s] = *(const bf16x8*)(qrow + s * 16 + hi * 8);

  const short* kbase = qkv + (size_t)(b * 1024) * 2304 + 768 + h * 64;
  const short* vbase = vT + (size_t)bh * 64 * 1024;

  float m_run = -1e30f, l_run = 0.0f;
  f32x16 ya0, ya1;
  #pragma unroll
  for (int r = 0; r < 16; r++) { ya0[r] = 0.0f; ya1[r] = 0.0f; }

  for (int jt = 0; jt <= it; ++jt) {
    const int J0 = jt * 32;
    const int D0 = I0 - J0 + 1023;
    // --- rpe band: G[i][m] = q_i . tbl[D0-31+m], m in [0,63] ---
    #pragma unroll
    for (int cb = 0; cb < 2; ++cb) {
      f32x16 g;
      #pragma unroll
      for (int r = 0; r < 16; r++) g[r] = 0.0f;
      int trow = D0 - 31 + cb * 32 + li;
      trow = trow > 2046 ? 2046 : trow;
      const short* tb = tbl + (size_t)trow * 64;
      #pragma unroll
      for (int s = 0; s < 4; s++) {
        bf16x8 tf = *(const bf16x8*)(tb + s * 16 + hi * 8);
        g = __builtin_amdgcn_mfma_f32_32x32x16_bf16(tf, qf[s], g, 0, 0, 0);
      }
      #pragma unroll
      for (int r = 0; r < 16; r++) {
        const int ml = (r & 3) + 8 * (r >> 2) + 4 * hi;
        G[li * 65 + cb * 32 + ml] = g[r];
      }
    }
    // --- S^T = K . Q^T ---
    f32x16 sa;
    #pragma unroll
    for (int r = 0; r < 16; r++) sa[r] = 0.0f;
    const short* kb = kbase + (size_t)(J0 + li) * 2304;
    #pragma unroll
    for (int s = 0; s < 4; s++) {
      bf16x8 kf = *(const bf16x8*)(kb + s * 16 + hi * 8);
      sa = __builtin_amdgcn_mfma_f32_32x32x16_bf16(kf, qf[s], sa, 0, 0, 0);
    }
    __syncthreads();
    // --- gather rpe, scale, mask, online softmax (lane owns row i=li) ---
    const int gi = I0 + li;
    float sv[16];
    float mx = -1e30f;
    #pragma unroll
    for (int r = 0; r < 16; r++) {
      const int j = (r & 3) + 8 * (r >> 2) + 4 * hi;
      float v = (sa[r] + G[li * 65 + (li - j + 31)]) * 0.125f;
      v = (J0 + j <= gi) ? v : -1e30f;
      sv[r] = v;
      mx = fmaxf(mx, v);
    }
    mx = fmaxf(mx, __shfl_xor(mx, 32));
    const float mnew = fmaxf(m_run, mx);
    const float alpha = __expf(m_run - mnew);
    float psum = 0.0f;
    unsigned pw[8];
    #pragma unroll
    for (int r = 0; r < 16; r += 2) {
      const float p0 = __expf(sv[r] - mnew);
      const float p1 = __expf(sv[r + 1] - mnew);
      psum += p0 + p1;
      pw[r >> 1] = (unsigned)(unsigned short)f2bf(p0) |
                   ((unsigned)(unsigned short)f2bf(p1) << 16);
    }
    psum += __shfl_xor(psum, 32);
    l_run = l_run * alpha + psum;
    m_run = mnew;
    if (hi == 0) fl[li] = alpha;
    #pragma unroll
    for (int r = 0; r < 16; r += 2) {
      const int j = (r & 3) + 8 * (r >> 2) + 4 * hi;
      *(unsigned*)&P[li * 40 + j] = pw[r >> 1];
    }
    __syncthreads();
    // --- rescale Y acc (rows of Y = i, via LDS broadcast) ---
    #pragma unroll
    for (int r = 0; r < 16; r++) {
      const float a = fl[(r & 3) + 8 * (r >> 2) + 4 * hi];
      ya0[r] *= a;
      ya1[r] *= a;
    }
    // --- PV: Y += P . V ---
    #pragma unroll
    for (int s = 0; s < 2; s++) {
      bf16x8 pf = *(const bf16x8*)&P[li * 40 + s * 16 + hi * 8];
      bf16x8 v0 = *(const bf16x8*)(vbase + (size_t)li * 1024 + J0 + s * 16 + hi * 8);
      bf16x8 v1 = *(const bf16x8*)(vbase + (size_t)(32 + li) * 1024 + J0 + s * 16 + hi * 8);
      ya0 = __builtin_amdgcn_mfma_f32_32x32x16_bf16(pf, v0, ya0, 0, 0, 0);
      ya1 = __builtin_amdgcn_mfma_f32_32x32x16_bf16(pf, v1, ya1, 0, 0, 0);
    }
    __syncthreads();
  }
  if (hi == 0) fl[li] = l_run;
  __syncthreads();
  short* yb = yout + (size_t)(b * 1024 + I0) * 768 + h * 64;
  #pragma unroll
  for (int r = 0; r < 16; r++) {
    const int row = (r & 3) + 8 * (r >> 2) + 4 * hi;
    const float linv = 1.0f / fl[row];
    yb[(size_t)row * 768 + li]      = f2bf(ya0[r] * linv);
    yb[(size_t)row * 768 + 32 + li] = f2bf(ya1[r] * linv);
  }
}

// ---------------- launch ----------------
extern "C" void kernel_launch(void* const* d_in, const int* in_sizes, int n_in,
                              void* d_out, int out_size, void* d_ws, size_t ws_size,
                              hipStream_t stream) {
  const float* x       = (const float*)d_in[0];
  const float* ln1_w   = (const float*)d_in[1];
  const float* w_attn  = (const float*)d_in[2];
  // d_in[3] = w_pos (dead code in reference)
  const float* w_cproj = (const float*)d_in[4];
  const float* ln2_w   = (const float*)d_in[5];
  const float* w_fc    = (const float*)d_in[6];
  const float* w_mproj = (const float*)d_in[7];
  float* out = (float*)d_out;
  char* ws = (char*)d_ws;

  short* wT_attn  = (short*)(ws + 0);          // [2304][768]
  short* wT_cproj = (short*)(ws + 3538944);    // [768][768]
  short* wT_fc    = (short*)(ws + 4718592);    // [3072][768]
  short* wT_mproj = (short*)(ws + 9437184);    // [768][3072]
  short* tbl      = (short*)(ws + 14155776);   // [2048][64] (rows 0..2046 valid)
  short* h_bf     = (short*)(ws + 14417920);   // [4096][768]
  short* qkv_bf   = (short*)(ws + 20709376);   // [4096][2304]
  short* vT       = (short*)(ws + 39583744);   // [48][64][1024]
  short* y_att    = (short*)(ws + 45875200);   // [4096][768]
  short* h2_bf    = (short*)(ws + 52166656);   // [4096][768]
  short* hfc_bf   = (short*)(ws + 58458112);   // [4096][3072]

  // weight prep
  wtrans_kernel<<<dim3(72, 24), 256, 0, stream>>>(w_attn, wT_attn, 768, 2304);
  wtrans_kernel<<<dim3(24, 24), 256, 0, stream>>>(w_cproj, wT_cproj, 768, 768);
  wtrans_kernel<<<dim3(96, 24), 256, 0, stream>>>(w_fc, wT_fc, 768, 3072);
  wtrans_kernel<<<dim3(24, 96), 256, 0, stream>>>(w_mproj, wT_mproj, 3072, 768);
  rpe_kernel<<<512, 256, 0, stream>>>(tbl);

  // attention branch
  ln_kernel<<<4096, 256, 0, stream>>>(x, ln1_w, h_bf);
  gemm_bt<0><<<dim3(18, 32), 256, 0, stream>>>(h_bf, wT_attn, nullptr, nullptr,
                                               qkv_bf, 4096, 2304, 768);
  vtrans_kernel<<<768, 256, 0, stream>>>(qkv_bf, vT);
  attn_kernel<<<1536, 64, 0, stream>>>(qkv_bf, vT, tbl, y_att);
  gemm_bt<1><<<dim3(6, 32), 256, 0, stream>>>(y_att, wT_cproj, x, out,
                                              nullptr, 4096, 768, 768);
  // MLP branch
  ln_kernel<<<4096, 256, 0, stream>>>(out, ln2_w, h2_bf);
  gemm_bt<2><<<dim3(24, 32), 256, 0, stream>>>(h2_bf, wT_fc, nullptr, nullptr,
                                               hfc_bf, 4096, 3072, 768);
  gemm_bt<1><<<dim3(6, 32), 256, 0, stream>>>(hfc_bf, wT_mproj, out, out,
                                              nullptr, 4096, 768, 3072);
}

// Round 2
// 282.945 us; speedup vs baseline: 1.1697x; 1.1697x over previous
//
#include <hip/hip_runtime.h>
#include <math.h>

typedef __attribute__((ext_vector_type(8))) short bf16x8;
typedef __attribute__((ext_vector_type(4))) float f32x4;
typedef __attribute__((ext_vector_type(16))) float f32x16;

__device__ inline short f2bf(float f) {
  unsigned u = __builtin_bit_cast(unsigned, f);
  u = u + 0x7fffu + ((u >> 16) & 1u);
  return (short)(u >> 16);
}
__device__ inline float bf2f(short s) {
  return __builtin_bit_cast(float, ((unsigned)(unsigned short)s) << 16);
}

// ---------------- weight transpose fp32[K,N] -> bf16[N,K] ----------------
__global__ __launch_bounds__(256) void wtrans_kernel(
    const float* __restrict__ in, short* __restrict__ out, int K, int N) {
  __shared__ float tile[32][33];
  const int tx = threadIdx.x & 31, ty = threadIdx.x >> 5;
  const int n0 = blockIdx.x * 32, k0 = blockIdx.y * 32;
  #pragma unroll
  for (int r = ty; r < 32; r += 8)
    tile[r][tx] = in[(size_t)(k0 + r) * N + n0 + tx];
  __syncthreads();
  #pragma unroll
  for (int r = ty; r < 32; r += 8)
    out[(size_t)(n0 + r) * K + k0 + tx] = f2bf(tile[tx][r]);
}

// ---------------- sinusoidal rpe table -> bf16 [2047][64] ----------------
__global__ __launch_bounds__(256) void rpe_kernel(short* __restrict__ tbl) {
  const int idx = blockIdx.x * 256 + threadIdx.x;
  if (idx >= 2047 * 64) return;
  const int row = idx >> 6, c = idx & 63;
  const float dist = (float)(row - 1023);
  const float inv = powf(10000.0f, -(float)(c & 31) * (1.0f / 32.0f));
  const float f = dist * inv;
  tbl[idx] = f2bf((c < 32) ? sinf(f) : cosf(f));
}

// ---------------- LayerNorm fp32 row(768) -> bf16 ----------------
__global__ __launch_bounds__(256) void ln_kernel(
    const float* __restrict__ x, const float* __restrict__ w,
    short* __restrict__ out) {
  const int row = blockIdx.x, tid = threadIdx.x;
  const float* xr = x + (size_t)row * 768;
  float v0 = xr[tid], v1 = xr[tid + 256], v2 = xr[tid + 512];
  float s = v0 + v1 + v2;
  #pragma unroll
  for (int o = 1; o < 64; o <<= 1) s += __shfl_xor(s, o);
  __shared__ float red[8];
  const int wv = tid >> 6;
  if ((tid & 63) == 0) red[wv] = s;
  __syncthreads();
  const float mean = (red[0] + red[1] + red[2] + red[3]) * (1.0f / 768.0f);
  v0 -= mean; v1 -= mean; v2 -= mean;
  float q = v0 * v0 + v1 * v1 + v2 * v2;
  #pragma unroll
  for (int o = 1; o < 64; o <<= 1) q += __shfl_xor(q, o);
  if ((tid & 63) == 0) red[4 + wv] = q;
  __syncthreads();
  const float var = (red[4] + red[5] + red[6] + red[7]) * (1.0f / 768.0f);
  const float inv = 1.0f / sqrtf(var + 1e-5f);
  out[(size_t)row * 768 + tid]       = f2bf(v0 * inv * w[tid]);
  out[(size_t)row * 768 + tid + 256] = f2bf(v1 * inv * w[tid + 256]);
  out[(size_t)row * 768 + tid + 512] = f2bf(v2 * inv * w[tid + 512]);
}

// ---------------- V transpose: qkv v-part -> vT[b,h,d,t] ----------------
__global__ __launch_bounds__(256) void vtrans_kernel(
    const short* __restrict__ qkv, short* __restrict__ vT) {
  __shared__ short tile[64][65];
  const int blk = blockIdx.x;
  const int bh = blk >> 4, t0 = (blk & 15) * 64;
  const int b = bh / 12, h = bh % 12;
  const int tx = threadIdx.x & 63, ty = threadIdx.x >> 6;
  const short* src = qkv + (size_t)(b * 1024 + t0) * 2304 + 1536 + h * 64;
  #pragma unroll
  for (int r = ty; r < 64; r += 4)
    tile[r][tx] = src[(size_t)r * 2304 + tx];
  __syncthreads();
  short* dst = vT + (size_t)bh * 64 * 1024 + t0;
  #pragma unroll
  for (int r = ty; r < 64; r += 4)
    dst[(size_t)r * 1024 + tx] = tile[tx][r];
}

// ---------------- GEMM: C[M,N] = A[M,K](bf16) x Bt[N,K](bf16) ----------------
// EPI 0: store bf16   EPI 1: fp32 out = res + acc   EPI 2: bf16 gelu(acc)
template <int EPI, int BM, int BN>
__global__ __launch_bounds__(256) void gemm_bt(
    const short* __restrict__ A, const short* __restrict__ Bt,
    const float* __restrict__ res, float* __restrict__ outF,
    short* __restrict__ outB, int M, int N, int K) {
  __shared__ short As[BM * 40];
  __shared__ short Bs[BN * 40];
  constexpr int WM = BM / 2, WN = BN / 2;
  constexpr int MI = WM / 16, NJ = WN / 16;
  const int tid = threadIdx.x;
  const int w = tid >> 6, lane = tid & 63;
  const int m0 = blockIdx.y * BM, n0 = blockIdx.x * BN;
  const int wm = (w >> 1) * WM, wn = (w & 1) * WN;
  f32x4 acc[MI][NJ];
  #pragma unroll
  for (int i = 0; i < MI; i++)
    #pragma unroll
    for (int j = 0; j < NJ; j++)
      #pragma unroll
      for (int r = 0; r < 4; r++) acc[i][j][r] = 0.0f;

  for (int kt = 0; kt < K; kt += 32) {
    __syncthreads();
    #pragma unroll
    for (int p = 0; p < BM / 64; ++p) {
      const int li16 = p * 256 + tid;
      const int row = li16 >> 2;
      const int kp = (li16 & 3) * 8;
      *(int4*)&As[row * 40 + kp] =
          *(const int4*)(A + (size_t)(m0 + row) * K + kt + kp);
    }
    #pragma unroll
    for (int p = 0; p < BN / 64; ++p) {
      const int li16 = p * 256 + tid;
      const int row = li16 >> 2;
      const int kp = (li16 & 3) * 8;
      *(int4*)&Bs[row * 40 + kp] =
          *(const int4*)(Bt + (size_t)(n0 + row) * K + kt + kp);
    }
    __syncthreads();
    bf16x8 af[MI], bfr[NJ];
    #pragma unroll
    for (int i = 0; i < MI; i++)
      af[i]  = *(const bf16x8*)&As[(wm + i * 16 + (lane & 15)) * 40 + (lane >> 4) * 8];
    #pragma unroll
    for (int j = 0; j < NJ; j++)
      bfr[j] = *(const bf16x8*)&Bs[(wn + j * 16 + (lane & 15)) * 40 + (lane >> 4) * 8];
    #pragma unroll
    for (int i = 0; i < MI; i++)
      #pragma unroll
      for (int j = 0; j < NJ; j++)
        acc[i][j] = __builtin_amdgcn_mfma_f32_16x16x32_bf16(af[i], bfr[j],
                                                            acc[i][j], 0, 0, 0);
  }
  const int r0 = (lane >> 4) * 4, cl = lane & 15;
  #pragma unroll
  for (int i = 0; i < MI; i++) {
    #pragma unroll
    for (int j = 0; j < NJ; j++) {
      const int gm = m0 + wm + i * 16 + r0;
      const int gn = n0 + wn + j * 16 + cl;
      #pragma unroll
      for (int r = 0; r < 4; r++) {
        const size_t idx = (size_t)(gm + r) * N + gn;
        const float v = acc[i][j][r];
        if constexpr (EPI == 0) {
          outB[idx] = f2bf(v);
        } else if constexpr (EPI == 1) {
          outF[idx] = res[idx] + v;
        } else {
          outB[idx] = f2bf(0.5f * v * (1.0f + erff(v * 0.70710678118f)));
        }
      }
    }
  }
}

// ---------------- attention partials: split-j flash chunks ----------------
// block = ((bh*32 + it)*4 + c); chunk c covers jt in [8c, min(8c+7, it)].
// 1 wave. Swapped-operand MFMA: S^T = mfma(K,Q), lane owns query row li.
__global__ __launch_bounds__(64) void attn_part(
    const short* __restrict__ qkv, const short* __restrict__ vT,
    const short* __restrict__ tbl, float* __restrict__ mpart,
    float* __restrict__ lpart, short* __restrict__ Ypart) {
  __shared__ float G[32 * 65];
  __shared__ float fl[32];
  __shared__ short P[32 * 40];
  const int blk = blockIdx.x;
  const int c = blk & 3;
  const int it = (blk >> 2) & 31;
  const int bh = blk >> 7;
  if (c > (it >> 3)) return;
  const int b = bh / 12, h = bh % 12;
  const int I0 = it * 32;
  const int lane = threadIdx.x;
  const int li = lane & 31, hi = lane >> 5;

  const short* qrow = qkv + (size_t)(b * 1024 + I0 + li) * 2304 + h * 64;
  bf16x8 qf[4];
  #pragma unroll
  for (int s = 0; s < 4; s++) qf[s] = *(const bf16x8*)(qrow + s * 16 + hi * 8);

  const short* kbase = qkv + (size_t)(b * 1024) * 2304 + 768 + h * 64;
  const short* vbase = vT + (size_t)bh * 64 * 1024;

  float m_run = -1e30f, l_run = 0.0f;
  f32x16 ya0, ya1;
  #pragma unroll
  for (int r = 0; r < 16; r++) { ya0[r] = 0.0f; ya1[r] = 0.0f; }

  const int jt0 = c * 8;
  const int jt1 = (c * 8 + 7 < it) ? (c * 8 + 7) : it;
  for (int jt = jt0; jt <= jt1; ++jt) {
    const int J0 = jt * 32;
    const int D0 = I0 - J0 + 1023;
    // --- rpe band: G[i][m] = q_i . tbl[D0-31+m], m in [0,63] ---
    #pragma unroll
    for (int cb = 0; cb < 2; ++cb) {
      f32x16 g;
      #pragma unroll
      for (int r = 0; r < 16; r++) g[r] = 0.0f;
      int trow = D0 - 31 + cb * 32 + li;
      trow = trow > 2046 ? 2046 : trow;
      const short* tb = tbl + (size_t)trow * 64;
      #pragma unroll
      for (int s = 0; s < 4; s++) {
        bf16x8 tf = *(const bf16x8*)(tb + s * 16 + hi * 8);
        g = __builtin_amdgcn_mfma_f32_32x32x16_bf16(tf, qf[s], g, 0, 0, 0);
      }
      #pragma unroll
      for (int r = 0; r < 16; r++) {
        const int ml = (r & 3) + 8 * (r >> 2) + 4 * hi;
        G[li * 65 + cb * 32 + ml] = g[r];
      }
    }
    // --- S^T = K . Q^T ---
    f32x16 sa;
    #pragma unroll
    for (int r = 0; r < 16; r++) sa[r] = 0.0f;
    const short* kb = kbase + (size_t)(J0 + li) * 2304;
    #pragma unroll
    for (int s = 0; s < 4; s++) {
      bf16x8 kf = *(const bf16x8*)(kb + s * 16 + hi * 8);
      sa = __builtin_amdgcn_mfma_f32_32x32x16_bf16(kf, qf[s], sa, 0, 0, 0);
    }
    __syncthreads();
    // --- gather rpe, scale, mask, online softmax (lane owns row i=li) ---
    const int gi = I0 + li;
    float sv[16];
    float mx = -1e30f;
    #pragma unroll
    for (int r = 0; r < 16; r++) {
      const int j = (r & 3) + 8 * (r >> 2) + 4 * hi;
      float v = (sa[r] + G[li * 65 + (li - j + 31)]) * 0.125f;
      v = (J0 + j <= gi) ? v : -1e30f;
      sv[r] = v;
      mx = fmaxf(mx, v);
    }
    mx = fmaxf(mx, __shfl_xor(mx, 32));
    const float mnew = fmaxf(m_run, mx);
    const float alpha = __expf(m_run - mnew);
    float psum = 0.0f;
    unsigned pw[8];
    #pragma unroll
    for (int r = 0; r < 16; r += 2) {
      const float p0 = __expf(sv[r] - mnew);
      const float p1 = __expf(sv[r + 1] - mnew);
      psum += p0 + p1;
      pw[r >> 1] = (unsigned)(unsigned short)f2bf(p0) |
                   ((unsigned)(unsigned short)f2bf(p1) << 16);
    }
    psum += __shfl_xor(psum, 32);
    l_run = l_run * alpha + psum;
    m_run = mnew;
    if (hi == 0) fl[li] = alpha;
    #pragma unroll
    for (int r = 0; r < 16; r += 2) {
      const int j = (r & 3) + 8 * (r >> 2) + 4 * hi;
      *(unsigned*)&P[li * 40 + j] = pw[r >> 1];
    }
    __syncthreads();
    // --- rescale Y acc ---
    #pragma unroll
    for (int r = 0; r < 16; r++) {
      const float a = fl[(r & 3) + 8 * (r >> 2) + 4 * hi];
      ya0[r] *= a;
      ya1[r] *= a;
    }
    // --- PV: Y += P . V ---
    #pragma unroll
    for (int s = 0; s < 2; s++) {
      bf16x8 pf = *(const bf16x8*)&P[li * 40 + s * 16 + hi * 8];
      bf16x8 v0 = *(const bf16x8*)(vbase + (size_t)li * 1024 + J0 + s * 16 + hi * 8);
      bf16x8 v1 = *(const bf16x8*)(vbase + (size_t)(32 + li) * 1024 + J0 + s * 16 + hi * 8);
      ya0 = __builtin_amdgcn_mfma_f32_32x32x16_bf16(pf, v0, ya0, 0, 0, 0);
      ya1 = __builtin_amdgcn_mfma_f32_32x32x16_bf16(pf, v1, ya1, 0, 0, 0);
    }
    __syncthreads();
  }
  // --- write partials: m, l per row; unnormalized Y (bf16) ---
  if (hi == 0) {
    mpart[(size_t)blk * 32 + li] = m_run;
    lpart[(size_t)blk * 32 + li] = l_run;
  }
  short* yb = Ypart + (size_t)blk * 2048;
  #pragma unroll
  for (int r = 0; r < 16; r++) {
    const int row = (r & 3) + 8 * (r >> 2) + 4 * hi;
    yb[row * 64 + li]      = f2bf(ya0[r]);
    yb[row * 64 + 32 + li] = f2bf(ya1[r]);
  }
}

// ---------------- attention combine: merge <=4 chunks ----------------
__global__ __launch_bounds__(256) void attn_combine(
    const float* __restrict__ mpart, const float* __restrict__ lpart,
    const short* __restrict__ Ypart, short* __restrict__ yout) {
  const int blk = blockIdx.x;  // bh*32 + it
  const int it = blk & 31, bh = blk >> 5;
  const int b = bh / 12, h = bh % 12;
  const int nc = (it >> 3) + 1;
  const int row = threadIdx.x >> 3;
  const int c0 = (threadIdx.x & 7) * 8;
  const int base = blk * 4;
  float mc[4], lc[4];
  #pragma unroll
  for (int c = 0; c < 4; ++c) {
    mc[c] = (c < nc) ? mpart[(base + c) * 32 + row] : -1e30f;
    lc[c] = (c < nc) ? lpart[(base + c) * 32 + row] : 0.0f;
  }
  const float m = fmaxf(fmaxf(mc[0], mc[1]), fmaxf(mc[2], mc[3]));
  float wgt[4];
  float L = 0.0f;
  #pragma unroll
  for (int c = 0; c < 4; ++c) {
    wgt[c] = __expf(mc[c] - m);
    L += lc[c] * wgt[c];
  }
  const float inv = 1.0f / L;
  float y[8];
  #pragma unroll
  for (int r = 0; r < 8; r++) y[r] = 0.0f;
  #pragma unroll
  for (int c = 0; c < 4; ++c) {
    if (c < nc) {
      bf16x8 v = *(const bf16x8*)(Ypart + ((size_t)(base + c) * 32 + row) * 64 + c0);
      #pragma unroll
      for (int r = 0; r < 8; r++) y[r] += bf2f(v[r]) * wgt[c];
    }
  }
  short* dst = yout + (size_t)(b * 1024 + it * 32 + row) * 768 + h * 64 + c0;
  #pragma unroll
  for (int r = 0; r < 8; r++) dst[r] = f2bf(y[r] * inv);
}

// ---------------- launch ----------------
extern "C" void kernel_launch(void* const* d_in, const int* in_sizes, int n_in,
                              void* d_out, int out_size, void* d_ws, size_t ws_size,
                              hipStream_t stream) {
  const float* x       = (const float*)d_in[0];
  const float* ln1_w   = (const float*)d_in[1];
  const float* w_attn  = (const float*)d_in[2];
  // d_in[3] = w_pos (dead code in reference)
  const float* w_cproj = (const float*)d_in[4];
  const float* ln2_w   = (const float*)d_in[5];
  const float* w_fc    = (const float*)d_in[6];
  const float* w_mproj = (const float*)d_in[7];
  float* out = (float*)d_out;
  char* ws = (char*)d_ws;

  short* wT_attn  = (short*)(ws + 0);          // [2304][768]
  short* wT_cproj = (short*)(ws + 3538944);    // [768][768]
  short* wT_fc    = (short*)(ws + 4718592);    // [3072][768]
  short* wT_mproj = (short*)(ws + 9437184);    // [768][3072]
  short* tbl      = (short*)(ws + 14155776);   // [2048][64] (rows 0..2046 valid)
  short* h_bf     = (short*)(ws + 14417920);   // [4096][768]
  short* qkv_bf   = (short*)(ws + 20709376);   // [4096][2304]
  short* vT       = (short*)(ws + 39583744);   // [48][64][1024]
  short* y_att    = (short*)(ws + 45875200);   // [4096][768]
  short* h2_bf    = (short*)(ws + 52166656);   // [4096][768]
  short* hfc_bf   = (short*)(ws + 58458112);   // [4096][3072]
  // attention partials alias the (not-yet-live) MLP buffers:
  float* mpart = (float*)(ws + 52166656);             // [6144][32] f32
  float* lpart = (float*)(ws + 52166656 + 786432);    // [6144][32] f32
  short* Ypart = (short*)(ws + 58458112);             // [6144][32][64] bf16

  // weight prep
  wtrans_kernel<<<dim3(72, 24), 256, 0, stream>>>(w_attn, wT_attn, 768, 2304);
  wtrans_kernel<<<dim3(24, 24), 256, 0, stream>>>(w_cproj, wT_cproj, 768, 768);
  wtrans_kernel<<<dim3(96, 24), 256, 0, stream>>>(w_fc, wT_fc, 768, 3072);
  wtrans_kernel<<<dim3(24, 96), 256, 0, stream>>>(w_mproj, wT_mproj, 3072, 768);
  rpe_kernel<<<512, 256, 0, stream>>>(tbl);

  // attention branch
  ln_kernel<<<4096, 256, 0, stream>>>(x, ln1_w, h_bf);
  gemm_bt<0, 128, 128><<<dim3(18, 32), 256, 0, stream>>>(
      h_bf, wT_attn, nullptr, nullptr, qkv_bf, 4096, 2304, 768);
  vtrans_kernel<<<768, 256, 0, stream>>>(qkv_bf, vT);
  attn_part<<<6144, 64, 0, stream>>>(qkv_bf, vT, tbl, mpart, lpart, Ypart);
  attn_combine<<<1536, 256, 0, stream>>>(mpart, lpart, Ypart, y_att);
  gemm_bt<1, 64, 64><<<dim3(12, 64), 256, 0, stream>>>(
      y_att, wT_cproj, x, out, nullptr, 4096, 768, 768);
  // MLP branch
  ln_kernel<<<4096, 256, 0, stream>>>(out, ln2_w, h2_bf);
  gemm_bt<2, 128, 128><<<dim3(24, 32), 256, 0, stream>>>(
      h2_bf, wT_fc, nullptr, nullptr, hfc_bf, 4096, 3072, 768);
  gemm_bt<1, 64, 64><<<dim3(12, 64), 256, 0, stream>>>(
      hfc_bf, wT_mproj, out, out, nullptr, 4096, 768, 3072);
}

// Round 3
// 242.548 us; speedup vs baseline: 1.3645x; 1.1666x over previous
//
#include <hip/hip_runtime.h>
#include <math.h>

typedef __attribute__((ext_vector_type(8))) short bf16x8;
typedef __attribute__((ext_vector_type(4))) float f32x4;
typedef __attribute__((ext_vector_type(16))) float f32x16;

__device__ inline short f2bf(float f) {
  unsigned u = __builtin_bit_cast(unsigned, f);
  u = u + 0x7fffu + ((u >> 16) & 1u);
  return (short)(u >> 16);
}
__device__ inline float bf2f(short s) {
  return __builtin_bit_cast(float, ((unsigned)(unsigned short)s) << 16);
}

// async global->LDS, 16B per lane. lds base must be wave-uniform.
__device__ inline void gload16(const short* g, short* l) {
  __builtin_amdgcn_global_load_lds(
      (const __attribute__((address_space(1))) unsigned*)g,
      (__attribute__((address_space(3))) unsigned*)l, 16, 0, 0);
}

// ---------------- weight transpose fp32[K,N] -> bf16[N,K] ----------------
__global__ __launch_bounds__(256) void wtrans_kernel(
    const float* __restrict__ in, short* __restrict__ out, int K, int N) {
  __shared__ float tile[32][33];
  const int tx = threadIdx.x & 31, ty = threadIdx.x >> 5;
  const int n0 = blockIdx.x * 32, k0 = blockIdx.y * 32;
  #pragma unroll
  for (int r = ty; r < 32; r += 8)
    tile[r][tx] = in[(size_t)(k0 + r) * N + n0 + tx];
  __syncthreads();
  #pragma unroll
  for (int r = ty; r < 32; r += 8)
    out[(size_t)(n0 + r) * K + k0 + tx] = f2bf(tile[tx][r]);
}

// ---------------- sinusoidal rpe table -> bf16 [2047][64] ----------------
__global__ __launch_bounds__(256) void rpe_kernel(short* __restrict__ tbl) {
  const int idx = blockIdx.x * 256 + threadIdx.x;
  if (idx >= 2047 * 64) return;
  const int row = idx >> 6, c = idx & 63;
  const float dist = (float)(row - 1023);
  const float inv = powf(10000.0f, -(float)(c & 31) * (1.0f / 32.0f));
  const float f = dist * inv;
  tbl[idx] = f2bf((c < 32) ? sinf(f) : cosf(f));
}

// ---------------- LayerNorm fp32 row(768) -> bf16 ----------------
__global__ __launch_bounds__(256) void ln_kernel(
    const float* __restrict__ x, const float* __restrict__ w,
    short* __restrict__ out) {
  const int row = blockIdx.x, tid = threadIdx.x;
  const float* xr = x + (size_t)row * 768;
  float v0 = xr[tid], v1 = xr[tid + 256], v2 = xr[tid + 512];
  float s = v0 + v1 + v2;
  #pragma unroll
  for (int o = 1; o < 64; o <<= 1) s += __shfl_xor(s, o);
  __shared__ float red[8];
  const int wv = tid >> 6;
  if ((tid & 63) == 0) red[wv] = s;
  __syncthreads();
  const float mean = (red[0] + red[1] + red[2] + red[3]) * (1.0f / 768.0f);
  v0 -= mean; v1 -= mean; v2 -= mean;
  float q = v0 * v0 + v1 * v1 + v2 * v2;
  #pragma unroll
  for (int o = 1; o < 64; o <<= 1) q += __shfl_xor(q, o);
  if ((tid & 63) == 0) red[4 + wv] = q;
  __syncthreads();
  const float var = (red[4] + red[5] + red[6] + red[7]) * (1.0f / 768.0f);
  const float inv = 1.0f / sqrtf(var + 1e-5f);
  out[(size_t)row * 768 + tid]       = f2bf(v0 * inv * w[tid]);
  out[(size_t)row * 768 + tid + 256] = f2bf(v1 * inv * w[tid + 256]);
  out[(size_t)row * 768 + tid + 512] = f2bf(v2 * inv * w[tid + 512]);
}

// ---------------- V transpose: qkv v-part -> vT[b,h,d,t] ----------------
__global__ __launch_bounds__(256) void vtrans_kernel(
    const short* __restrict__ qkv, short* __restrict__ vT) {
  __shared__ short tile[64][65];
  const int blk = blockIdx.x;
  const int bh = blk >> 4, t0 = (blk & 15) * 64;
  const int b = bh / 12, h = bh % 12;
  const int tx = threadIdx.x & 63, ty = threadIdx.x >> 6;
  const short* src = qkv + (size_t)(b * 1024 + t0) * 2304 + 1536 + h * 64;
  #pragma unroll
  for (int r = ty; r < 64; r += 4)
    tile[r][tx] = src[(size_t)r * 2304 + tx];
  __syncthreads();
  short* dst = vT + (size_t)bh * 64 * 1024 + t0;
  #pragma unroll
  for (int r = ty; r < 64; r += 4)
    dst[(size_t)r * 1024 + tx] = tile[tx][r];
}

// ---------------- GEMM: C[M,N] = A[M,K](bf16) x Bt[N,K](bf16) ----------------
// global_load_lds staging (m97 structure), linear LDS [rows][32].
// EPI 0: store bf16   EPI 1: fp32 out = res + acc   EPI 2: bf16 gelu(acc)
template <int EPI, int BM, int BN>
__global__ __launch_bounds__(256) void gemm_bt(
    const short* __restrict__ A, const short* __restrict__ Bt,
    const float* __restrict__ res, float* __restrict__ outF,
    short* __restrict__ outB, int M, int N, int K) {
  __shared__ __align__(16) short As[BM * 32];
  __shared__ __align__(16) short Bs[BN * 32];
  constexpr int WM = BM / 2, WN = BN / 2;
  constexpr int MI = WM / 16, NJ = WN / 16;
  const int tid = threadIdx.x;
  const int w = tid >> 6, lane = tid & 63;
  const int m0 = blockIdx.y * BM, n0 = blockIdx.x * BN;
  const int wm = (w >> 1) * WM, wn = (w & 1) * WN;
  const int lr = lane >> 2;          // staging row within 16-row group
  const int lc = (lane & 3) * 8;     // staging col (shorts)
  f32x4 acc[MI][NJ];
  #pragma unroll
  for (int i = 0; i < MI; i++)
    #pragma unroll
    for (int j = 0; j < NJ; j++)
      #pragma unroll
      for (int r = 0; r < 4; r++) acc[i][j][r] = 0.0f;

  for (int kt = 0; kt < K; kt += 32) {
    __syncthreads();
    #pragma unroll
    for (int p = 0; p < BM / 64; ++p) {
      const int row = p * 64 + w * 16 + lr;
      gload16(A + (size_t)(m0 + row) * K + kt + lc, As + p * 2048 + w * 512);
    }
    #pragma unroll
    for (int p = 0; p < BN / 64; ++p) {
      const int row = p * 64 + w * 16 + lr;
      gload16(Bt + (size_t)(n0 + row) * K + kt + lc, Bs + p * 2048 + w * 512);
    }
    __syncthreads();
    bf16x8 af[MI], bfr[NJ];
    #pragma unroll
    for (int i = 0; i < MI; i++)
      af[i]  = *(const bf16x8*)&As[(wm + i * 16 + (lane & 15)) * 32 + (lane >> 4) * 8];
    #pragma unroll
    for (int j = 0; j < NJ; j++)
      bfr[j] = *(const bf16x8*)&Bs[(wn + j * 16 + (lane & 15)) * 32 + (lane >> 4) * 8];
    #pragma unroll
    for (int i = 0; i < MI; i++)
      #pragma unroll
      for (int j = 0; j < NJ; j++)
        acc[i][j] = __builtin_amdgcn_mfma_f32_16x16x32_bf16(af[i], bfr[j],
                                                            acc[i][j], 0, 0, 0);
  }
  const int r0 = (lane >> 4) * 4, cl = lane & 15;
  #pragma unroll
  for (int i = 0; i < MI; i++) {
    #pragma unroll
    for (int j = 0; j < NJ; j++) {
      const int gm = m0 + wm + i * 16 + r0;
      const int gn = n0 + wn + j * 16 + cl;
      #pragma unroll
      for (int r = 0; r < 4; r++) {
        const size_t idx = (size_t)(gm + r) * N + gn;
        const float v = acc[i][j][r];
        if constexpr (EPI == 0) {
          outB[idx] = f2bf(v);
        } else if constexpr (EPI == 1) {
          outF[idx] = res[idx] + v;
        } else {
          outB[idx] = f2bf(0.5f * v * (1.0f + erff(v * 0.70710678118f)));
        }
      }
    }
  }
}

// ---------------- attention partials: split-j flash chunks (4 tiles/chunk) ----
// Compact grid: blk -> (bh, it, c); chunk c covers jt in [4c, min(4c+3, it)].
// 1 wave. Swapped-operand MFMA: S^T = mfma(K,Q), lane owns query row li.
__global__ __launch_bounds__(64) void attn_part(
    const short* __restrict__ qkv, const short* __restrict__ vT,
    const short* __restrict__ tbl, float* __restrict__ mpart,
    float* __restrict__ lpart, short* __restrict__ Ypart) {
  __shared__ __align__(16) float G[32 * 65];
  __shared__ float fl[32];
  __shared__ __align__(16) short P[32 * 40];
  const int blk = blockIdx.x;
  const int bh = blk / 144;
  const int rem = blk % 144;
  int g = 0;
  while (g < 7 && rem >= 2 * (g + 1) * (g + 2)) ++g;
  const int r2 = rem - 2 * g * (g + 1);
  const int it = g * 4 + r2 / (g + 1);
  const int c = r2 % (g + 1);
  const int b = bh / 12, h = bh % 12;
  const int I0 = it * 32;
  const int lane = threadIdx.x;
  const int li = lane & 31, hi = lane >> 5;

  const short* qrow = qkv + (size_t)(b * 1024 + I0 + li) * 2304 + h * 64;
  bf16x8 qf[4];
  #pragma unroll
  for (int s = 0; s < 4; s++) qf[s] = *(const bf16x8*)(qrow + s * 16 + hi * 8);

  const short* kbase = qkv + (size_t)(b * 1024) * 2304 + 768 + h * 64;
  const short* vbase = vT + (size_t)bh * 64 * 1024;

  float m_run = -1e30f, l_run = 0.0f;
  f32x16 ya0, ya1;
  #pragma unroll
  for (int r = 0; r < 16; r++) { ya0[r] = 0.0f; ya1[r] = 0.0f; }

  const int jt0 = c * 4;
  const int jt1 = (c * 4 + 3 < it) ? (c * 4 + 3) : it;

  // prefetch K for first tile
  bf16x8 kn[4];
  {
    const short* kb = kbase + (size_t)(jt0 * 32 + li) * 2304;
    #pragma unroll
    for (int s = 0; s < 4; s++) kn[s] = *(const bf16x8*)(kb + s * 16 + hi * 8);
  }

  for (int jt = jt0; jt <= jt1; ++jt) {
    const int J0 = jt * 32;
    const int D0 = I0 - J0 + 1023;
    // current K from prefetch
    bf16x8 kf[4];
    #pragma unroll
    for (int s = 0; s < 4; s++) kf[s] = kn[s];
    // issue next K prefetch (hidden under rpe MFMAs)
    if (jt < jt1) {
      const short* kb = kbase + (size_t)((jt + 1) * 32 + li) * 2304;
      #pragma unroll
      for (int s = 0; s < 4; s++) kn[s] = *(const bf16x8*)(kb + s * 16 + hi * 8);
    }
    // issue V loads for current tile early (used after softmax)
    bf16x8 vc[4];
    #pragma unroll
    for (int s = 0; s < 2; s++) {
      vc[s * 2]     = *(const bf16x8*)(vbase + (size_t)li * 1024 + J0 + s * 16 + hi * 8);
      vc[s * 2 + 1] = *(const bf16x8*)(vbase + (size_t)(32 + li) * 1024 + J0 + s * 16 + hi * 8);
    }
    // --- rpe band: G[i][m] = q_i . tbl[D0-31+m], m in [0,63] ---
    #pragma unroll
    for (int cb = 0; cb < 2; ++cb) {
      f32x16 gacc;
      #pragma unroll
      for (int r = 0; r < 16; r++) gacc[r] = 0.0f;
      int trow = D0 - 31 + cb * 32 + li;
      trow = trow > 2046 ? 2046 : trow;
      const short* tb = tbl + (size_t)trow * 64;
      #pragma unroll
      for (int s = 0; s < 4; s++) {
        bf16x8 tf = *(const bf16x8*)(tb + s * 16 + hi * 8);
        gacc = __builtin_amdgcn_mfma_f32_32x32x16_bf16(tf, qf[s], gacc, 0, 0, 0);
      }
      #pragma unroll
      for (int r = 0; r < 16; r++) {
        const int ml = (r & 3) + 8 * (r >> 2) + 4 * hi;
        G[li * 65 + cb * 32 + ml] = gacc[r];
      }
    }
    // --- S^T = K . Q^T ---
    f32x16 sa;
    #pragma unroll
    for (int r = 0; r < 16; r++) sa[r] = 0.0f;
    #pragma unroll
    for (int s = 0; s < 4; s++)
      sa = __builtin_amdgcn_mfma_f32_32x32x16_bf16(kf[s], qf[s], sa, 0, 0, 0);
    __syncthreads();
    // --- gather rpe, scale, mask, online softmax (lane owns row i=li) ---
    const int gi = I0 + li;
    float sv[16];
    float mx = -1e30f;
    #pragma unroll
    for (int r = 0; r < 16; r++) {
      const int j = (r & 3) + 8 * (r >> 2) + 4 * hi;
      float v = (sa[r] + G[li * 65 + (li - j + 31)]) * 0.125f;
      v = (J0 + j <= gi) ? v : -1e30f;
      sv[r] = v;
      mx = fmaxf(mx, v);
    }
    mx = fmaxf(mx, __shfl_xor(mx, 32));
    const float mnew = fmaxf(m_run, mx);
    const float alpha = __expf(m_run - mnew);
    float psum = 0.0f;
    unsigned pw[8];
    #pragma unroll
    for (int r = 0; r < 16; r += 2) {
      const float p0 = __expf(sv[r] - mnew);
      const float p1 = __expf(sv[r + 1] - mnew);
      psum += p0 + p1;
      pw[r >> 1] = (unsigned)(unsigned short)f2bf(p0) |
                   ((unsigned)(unsigned short)f2bf(p1) << 16);
    }
    psum += __shfl_xor(psum, 32);
    l_run = l_run * alpha + psum;
    m_run = mnew;
    if (hi == 0) fl[li] = alpha;
    #pragma unroll
    for (int r = 0; r < 16; r += 2) {
      const int j = (r & 3) + 8 * (r >> 2) + 4 * hi;
      *(unsigned*)&P[li * 40 + j] = pw[r >> 1];
    }
    __syncthreads();
    // --- rescale Y acc ---
    #pragma unroll
    for (int r = 0; r < 16; r++) {
      const float a = fl[(r & 3) + 8 * (r >> 2) + 4 * hi];
      ya0[r] *= a;
      ya1[r] *= a;
    }
    // --- PV: Y += P . V ---
    #pragma unroll
    for (int s = 0; s < 2; s++) {
      bf16x8 pf = *(const bf16x8*)&P[li * 40 + s * 16 + hi * 8];
      ya0 = __builtin_amdgcn_mfma_f32_32x32x16_bf16(pf, vc[s * 2], ya0, 0, 0, 0);
      ya1 = __builtin_amdgcn_mfma_f32_32x32x16_bf16(pf, vc[s * 2 + 1], ya1, 0, 0, 0);
    }
    __syncthreads();
  }
  // --- write partials: m, l per row; unnormalized Y (bf16) ---
  if (hi == 0) {
    mpart[(size_t)blk * 32 + li] = m_run;
    lpart[(size_t)blk * 32 + li] = l_run;
  }
  short* yb = Ypart + (size_t)blk * 2048;
  #pragma unroll
  for (int r = 0; r < 16; r++) {
    const int row = (r & 3) + 8 * (r >> 2) + 4 * hi;
    yb[row * 64 + li]      = f2bf(ya0[r]);
    yb[row * 64 + 32 + li] = f2bf(ya1[r]);
  }
}

// ---------------- attention combine: merge <=8 chunks ----------------
__global__ __launch_bounds__(256) void attn_combine(
    const float* __restrict__ mpart, const float* __restrict__ lpart,
    const short* __restrict__ Ypart, short* __restrict__ yout) {
  const int blk = blockIdx.x;  // bh*32 + it
  const int it = blk & 31, bh = blk >> 5;
  const int b = bh / 12, h = bh % 12;
  const int g = it >> 2;
  const int nc = g + 1;
  const int base = bh * 144 + 2 * g * (g + 1) + (it - g * 4) * (g + 1);
  const int row = threadIdx.x >> 3;
  const int c0 = (threadIdx.x & 7) * 8;
  float mv[8], lv[8], wgt[8];
  float m = -1e30f;
  #pragma unroll
  for (int cI = 0; cI < 8; ++cI) {
    mv[cI] = (cI < nc) ? mpart[(size_t)(base + cI) * 32 + row] : -1e30f;
    lv[cI] = (cI < nc) ? lpart[(size_t)(base + cI) * 32 + row] : 0.0f;
    m = fmaxf(m, mv[cI]);
  }
  float L = 0.0f;
  #pragma unroll
  for (int cI = 0; cI < 8; ++cI) {
    wgt[cI] = __expf(mv[cI] - m);
    L += lv[cI] * wgt[cI];
  }
  const float inv = 1.0f / L;
  float y[8];
  #pragma unroll
  for (int r = 0; r < 8; r++) y[r] = 0.0f;
  #pragma unroll
  for (int cI = 0; cI < 8; ++cI) {
    if (cI < nc) {
      bf16x8 v = *(const bf16x8*)(Ypart + ((size_t)(base + cI) * 32 + row) * 64 + c0);
      #pragma unroll
      for (int r = 0; r < 8; r++) y[r] += bf2f(v[r]) * wgt[cI];
    }
  }
  short* dst = yout + (size_t)(b * 1024 + it * 32 + row) * 768 + h * 64 + c0;
  #pragma unroll
  for (int r = 0; r < 8; r++) dst[r] = f2bf(y[r] * inv);
}

// ---------------- launch ----------------
extern "C" void kernel_launch(void* const* d_in, const int* in_sizes, int n_in,
                              void* d_out, int out_size, void* d_ws, size_t ws_size,
                              hipStream_t stream) {
  const float* x       = (const float*)d_in[0];
  const float* ln1_w   = (const float*)d_in[1];
  const float* w_attn  = (const float*)d_in[2];
  // d_in[3] = w_pos (dead code in reference)
  const float* w_cproj = (const float*)d_in[4];
  const float* ln2_w   = (const float*)d_in[5];
  const float* w_fc    = (const float*)d_in[6];
  const float* w_mproj = (const float*)d_in[7];
  float* out = (float*)d_out;
  char* ws = (char*)d_ws;

  short* wT_attn  = (short*)(ws + 0);          // [2304][768]
  short* wT_cproj = (short*)(ws + 3538944);    // [768][768]
  short* wT_fc    = (short*)(ws + 4718592);    // [3072][768]
  short* wT_mproj = (short*)(ws + 9437184);    // [768][3072]
  short* tbl      = (short*)(ws + 14155776);   // [2048][64] (rows 0..2046 valid)
  short* h_bf     = (short*)(ws + 14417920);   // [4096][768]
  short* qkv_bf   = (short*)(ws + 20709376);   // [4096][2304]
  short* vT       = (short*)(ws + 39583744);   // [48][64][1024]
  short* y_att    = (short*)(ws + 45875200);   // [4096][768]
  short* h2_bf    = (short*)(ws + 52166656);   // [4096][768]
  short* hfc_bf   = (short*)(ws + 58458112);   // [4096][3072]
  // attention partials alias the (not-yet-live) MLP buffers:
  float* mpart = (float*)(ws + 52166656);      // [6912][32] f32   (884,736 B)
  float* lpart = (float*)(ws + 53051392);      // [6912][32] f32   (884,736 B)
  short* Ypart = (short*)(ws + 53936128);      // [6912][32][64] bf16 (28,311,552 B)

  // weight prep
  wtrans_kernel<<<dim3(72, 24), 256, 0, stream>>>(w_attn, wT_attn, 768, 2304);
  wtrans_kernel<<<dim3(24, 24), 256, 0, stream>>>(w_cproj, wT_cproj, 768, 768);
  wtrans_kernel<<<dim3(96, 24), 256, 0, stream>>>(w_fc, wT_fc, 768, 3072);
  wtrans_kernel<<<dim3(24, 96), 256, 0, stream>>>(w_mproj, wT_mproj, 3072, 768);
  rpe_kernel<<<512, 256, 0, stream>>>(tbl);

  // attention branch
  ln_kernel<<<4096, 256, 0, stream>>>(x, ln1_w, h_bf);
  gemm_bt<0, 128, 128><<<dim3(18, 32), 256, 0, stream>>>(
      h_bf, wT_attn, nullptr, nullptr, qkv_bf, 4096, 2304, 768);
  vtrans_kernel<<<768, 256, 0, stream>>>(qkv_bf, vT);
  attn_part<<<6912, 64, 0, stream>>>(qkv_bf, vT, tbl, mpart, lpart, Ypart);
  attn_combine<<<1536, 256, 0, stream>>>(mpart, lpart, Ypart, y_att);
  gemm_bt<1, 64, 64><<<dim3(12, 64), 256, 0, stream>>>(
      y_att, wT_cproj, x, out, nullptr, 4096, 768, 768);
  // MLP branch
  ln_kernel<<<4096, 256, 0, stream>>>(out, ln2_w, h2_bf);
  gemm_bt<2, 128, 128><<<dim3(24, 32), 256, 0, stream>>>(
      h2_bf, wT_fc, nullptr, nullptr, hfc_bf, 4096, 3072, 768);
  gemm_bt<1, 64, 64><<<dim3(12, 64), 256, 0, stream>>>(
      hfc_bf, wT_mproj, out, out, nullptr, 4096, 768, 3072);
}

// Round 4
// 230.713 us; speedup vs baseline: 1.4345x; 1.0513x over previous
//
#include <hip/hip_runtime.h>
#include <math.h>

typedef __attribute__((ext_vector_type(8))) short bf16x8;
typedef __attribute__((ext_vector_type(4))) float f32x4;
typedef __attribute__((ext_vector_type(16))) float f32x16;
typedef __attribute__((ext_vector_type(4))) unsigned u32x4;

__device__ inline short f2bf(float f) {
  unsigned u = __builtin_bit_cast(unsigned, f);
  u = u + 0x7fffu + ((u >> 16) & 1u);
  return (short)(u >> 16);
}
__device__ inline float bf2f(short s) {
  return __builtin_bit_cast(float, ((unsigned)(unsigned short)s) << 16);
}

// async global->LDS, 16B per lane. lds base must be wave-uniform.
__device__ inline void gload16(const short* g, short* l) {
  __builtin_amdgcn_global_load_lds(
      (const __attribute__((address_space(1))) unsigned*)g,
      (__attribute__((address_space(3))) unsigned*)l, 16, 0, 0);
}

// ---------------- weight transpose fp32[K,N] -> bf16[N,K] ----------------
__global__ __launch_bounds__(256) void wtrans_kernel(
    const float* __restrict__ in, short* __restrict__ out, int K, int N) {
  __shared__ float tile[32][33];
  const int tx = threadIdx.x & 31, ty = threadIdx.x >> 5;
  const int n0 = blockIdx.x * 32, k0 = blockIdx.y * 32;
  #pragma unroll
  for (int r = ty; r < 32; r += 8)
    tile[r][tx] = in[(size_t)(k0 + r) * N + n0 + tx];
  __syncthreads();
  #pragma unroll
  for (int r = ty; r < 32; r += 8)
    out[(size_t)(n0 + r) * K + k0 + tx] = f2bf(tile[tx][r]);
}

// ---------------- K' table: ktab[j][0..31]=cos(j f_c), [32..63]=sin(j f_c) ----
__global__ __launch_bounds__(256) void ktab_kernel(short* __restrict__ ktab) {
  const int idx = blockIdx.x * 256 + threadIdx.x;  // 1024*32
  const int j = idx >> 5, cc = idx & 31;
  const float invf = exp2f(-(float)cc * (13.287712379549449f / 32.0f));
  const float ang = (float)j * invf;
  ktab[j * 64 + cc]      = f2bf(cosf(ang));
  ktab[j * 64 + 32 + cc] = f2bf(sinf(ang));
}

// ---------------- Q' from q: angle-sum folding of rpe ----------------
// Q'[i][cc]    = q_s*sin_i + q_c*cos_i   (pairs with cos_j)
// Q'[i][32+cc] = q_c*sin_i - q_s*cos_i   (pairs with sin_j)
__global__ __launch_bounds__(256) void qprime_kernel(
    const short* __restrict__ qkv, short* __restrict__ qpr) {
  const int idx = blockIdx.x * 256 + threadIdx.x;  // 48*1024*32
  const int cc = idx & 31;
  const int row = idx >> 5;            // bh*1024 + i
  const int i = row & 1023, bh = row >> 10;
  const int b = bh / 12, h = bh % 12;
  const float invf = exp2f(-(float)cc * (13.287712379549449f / 32.0f));
  const float ang = (float)i * invf;
  const float si = sinf(ang), co = cosf(ang);
  const short* q = qkv + (size_t)(b * 1024 + i) * 2304 + h * 64;
  const float qs = bf2f(q[cc]), qc = bf2f(q[32 + cc]);
  qpr[(size_t)row * 64 + cc]      = f2bf(qs * si + qc * co);
  qpr[(size_t)row * 64 + 32 + cc] = f2bf(qc * si - qs * co);
}

// ---------------- LayerNorm fp32 row(768) -> bf16 ----------------
__global__ __launch_bounds__(256) void ln_kernel(
    const float* __restrict__ x, const float* __restrict__ w,
    short* __restrict__ out) {
  const int row = blockIdx.x, tid = threadIdx.x;
  const float* xr = x + (size_t)row * 768;
  float v0 = xr[tid], v1 = xr[tid + 256], v2 = xr[tid + 512];
  float s = v0 + v1 + v2;
  #pragma unroll
  for (int o = 1; o < 64; o <<= 1) s += __shfl_xor(s, o);
  __shared__ float red[8];
  const int wv = tid >> 6;
  if ((tid & 63) == 0) red[wv] = s;
  __syncthreads();
  const float mean = (red[0] + red[1] + red[2] + red[3]) * (1.0f / 768.0f);
  v0 -= mean; v1 -= mean; v2 -= mean;
  float q = v0 * v0 + v1 * v1 + v2 * v2;
  #pragma unroll
  for (int o = 1; o < 64; o <<= 1) q += __shfl_xor(q, o);
  if ((tid & 63) == 0) red[4 + wv] = q;
  __syncthreads();
  const float var = (red[4] + red[5] + red[6] + red[7]) * (1.0f / 768.0f);
  const float inv = 1.0f / sqrtf(var + 1e-5f);
  out[(size_t)row * 768 + tid]       = f2bf(v0 * inv * w[tid]);
  out[(size_t)row * 768 + tid + 256] = f2bf(v1 * inv * w[tid + 256]);
  out[(size_t)row * 768 + tid + 512] = f2bf(v2 * inv * w[tid + 512]);
}

// ---------------- V transpose: qkv v-part -> vT[b,h,d,t] ----------------
__global__ __launch_bounds__(256) void vtrans_kernel(
    const short* __restrict__ qkv, short* __restrict__ vT) {
  __shared__ short tile[64][65];
  const int blk = blockIdx.x;
  const int bh = blk >> 4, t0 = (blk & 15) * 64;
  const int b = bh / 12, h = bh % 12;
  const int tx = threadIdx.x & 63, ty = threadIdx.x >> 6;
  const short* src = qkv + (size_t)(b * 1024 + t0) * 2304 + 1536 + h * 64;
  #pragma unroll
  for (int r = ty; r < 64; r += 4)
    tile[r][tx] = src[(size_t)r * 2304 + tx];
  __syncthreads();
  short* dst = vT + (size_t)bh * 64 * 1024 + t0;
  #pragma unroll
  for (int r = ty; r < 64; r += 4)
    dst[(size_t)r * 1024 + tx] = tile[tx][r];
}

// ---------------- GEMM: C[M,N] = A[M,K](bf16) x Bt[N,K](bf16) ----------------
// 2-phase double-buffered global_load_lds staging; ONE barrier per K-step.
// EPI 0: bf16 store  1: f32 out=res+acc  2: bf16 gelu  3: f32 split-K partial
template <int EPI, int BM, int BN>
__global__ __launch_bounds__(256) void gemm_bt(
    const short* __restrict__ A, const short* __restrict__ Bt,
    const float* __restrict__ res, float* __restrict__ outF,
    short* __restrict__ outB, int M, int N, int K, int lda, int ldb) {
  __shared__ __align__(16) short As[2][BM * 32];
  __shared__ __align__(16) short Bs[2][BN * 32];
  constexpr int WM = BM / 2, WN = BN / 2;
  constexpr int MI = WM / 16, NJ = WN / 16;
  const int tid = threadIdx.x;
  const int w = tid >> 6, lane = tid & 63;
  const int m0 = blockIdx.y * BM, n0 = blockIdx.x * BN;
  const int wm = (w >> 1) * WM, wn = (w & 1) * WN;
  const int lr = lane >> 2;
  const int lc = (lane & 3) * 8;
  if constexpr (EPI == 3) {
    A += (size_t)blockIdx.z * K;
    Bt += (size_t)blockIdx.z * K;
    outF += (size_t)blockIdx.z * M * N;
  }
  f32x4 acc[MI][NJ];
  #pragma unroll
  for (int i = 0; i < MI; i++)
    #pragma unroll
    for (int j = 0; j < NJ; j++)
      #pragma unroll
      for (int r = 0; r < 4; r++) acc[i][j][r] = 0.0f;

  const int nt = K / 32;
  // prologue stage into buf 0
  #pragma unroll
  for (int p = 0; p < BM / 64; ++p)
    gload16(A + (size_t)(m0 + p * 64 + w * 16 + lr) * lda + lc,
            &As[0][p * 2048 + w * 512]);
  #pragma unroll
  for (int p = 0; p < BN / 64; ++p)
    gload16(Bt + (size_t)(n0 + p * 64 + w * 16 + lr) * ldb + lc,
            &Bs[0][p * 2048 + w * 512]);
  __syncthreads();

  for (int t = 0; t < nt; ++t) {
    const int cur = t & 1;
    if (t + 1 < nt) {
      const int kt = (t + 1) * 32;
      #pragma unroll
      for (int p = 0; p < BM / 64; ++p)
        gload16(A + (size_t)(m0 + p * 64 + w * 16 + lr) * lda + kt + lc,
                &As[cur ^ 1][p * 2048 + w * 512]);
      #pragma unroll
      for (int p = 0; p < BN / 64; ++p)
        gload16(Bt + (size_t)(n0 + p * 64 + w * 16 + lr) * ldb + kt + lc,
                &Bs[cur ^ 1][p * 2048 + w * 512]);
    }
    bf16x8 af[MI], bfr[NJ];
    #pragma unroll
    for (int i = 0; i < MI; i++)
      af[i] = *(const bf16x8*)&As[cur][(wm + i * 16 + (lane & 15)) * 32 + (lane >> 4) * 8];
    #pragma unroll
    for (int j = 0; j < NJ; j++)
      bfr[j] = *(const bf16x8*)&Bs[cur][(wn + j * 16 + (lane & 15)) * 32 + (lane >> 4) * 8];
    #pragma unroll
    for (int i = 0; i < MI; i++)
      #pragma unroll
      for (int j = 0; j < NJ; j++)
        acc[i][j] = __builtin_amdgcn_mfma_f32_16x16x32_bf16(af[i], bfr[j],
                                                            acc[i][j], 0, 0, 0);
    __syncthreads();
  }
  const int r0 = (lane >> 4) * 4, cl = lane & 15;
  #pragma unroll
  for (int i = 0; i < MI; i++) {
    #pragma unroll
    for (int j = 0; j < NJ; j++) {
      const int gm = m0 + wm + i * 16 + r0;
      const int gn = n0 + wn + j * 16 + cl;
      #pragma unroll
      for (int r = 0; r < 4; r++) {
        const size_t idx = (size_t)(gm + r) * N + gn;
        const float v = acc[i][j][r];
        if constexpr (EPI == 0) {
          outB[idx] = f2bf(v);
        } else if constexpr (EPI == 1) {
          outF[idx] = res[idx] + v;
        } else if constexpr (EPI == 2) {
          outB[idx] = f2bf(0.5f * v * (1.0f + erff(v * 0.70710678118f)));
        } else {
          outF[idx] = v;
        }
      }
    }
  }
}

// ---------------- split-K reduce: out = res + sum_z Cp[z] ----------------
__global__ __launch_bounds__(256) void reduce_splitk(
    const float* __restrict__ Cp, const float* __restrict__ res,
    float* __restrict__ out) {
  const size_t i4 = ((size_t)blockIdx.x * 256 + threadIdx.x) * 4;
  float4 a = *(const float4*)(res + i4);
  #pragma unroll
  for (int z = 0; z < 4; ++z) {
    float4 p = *(const float4*)(Cp + (size_t)z * 3145728 + i4);
    a.x += p.x; a.y += p.y; a.z += p.z; a.w += p.w;
  }
  *(float4*)(out + i4) = a;
}

// ---------------- attention partials: zero-LDS flash chunks ----------------
// Head-dim-128 QK' (rpe folded in); permlane32_swap P redistribution.
__global__ __launch_bounds__(64) void attn_part(
    const short* __restrict__ qkv, const short* __restrict__ vT,
    const short* __restrict__ qpr, const short* __restrict__ ktab,
    float* __restrict__ mpart, float* __restrict__ lpart,
    short* __restrict__ Ypart) {
  const int blk = blockIdx.x;
  const int bh = blk / 144;
  const int rem = blk % 144;
  int g = 0;
  while (g < 7 && rem >= 2 * (g + 1) * (g + 2)) ++g;
  const int r2 = rem - 2 * g * (g + 1);
  const int it = g * 4 + r2 / (g + 1);
  const int c = r2 % (g + 1);
  const int b = bh / 12, h = bh % 12;
  const int I0 = it * 32;
  const int lane = threadIdx.x;
  const int li = lane & 31, hi = lane >> 5;

  // Qaug fragments: [q(64) | Q'(64)]
  const short* qrow = qkv + (size_t)(b * 1024 + I0 + li) * 2304 + h * 64;
  const short* qprow = qpr + ((size_t)bh * 1024 + I0 + li) * 64;
  bf16x8 qf[8];
  #pragma unroll
  for (int s = 0; s < 4; s++) {
    qf[s]     = *(const bf16x8*)(qrow + s * 16 + hi * 8);
    qf[4 + s] = *(const bf16x8*)(qprow + s * 16 + hi * 8);
  }
  const short* kbase = qkv + (size_t)(b * 1024) * 2304 + 768 + h * 64;
  const short* vbase = vT + (size_t)bh * 64 * 1024;

  float m_run = -1e30f, l_run = 0.0f;
  f32x16 ya0, ya1;
  #pragma unroll
  for (int r = 0; r < 16; r++) { ya0[r] = 0.0f; ya1[r] = 0.0f; }

  const int jt0 = c * 4;
  const int jt1 = (c * 4 + 3 < it) ? (c * 4 + 3) : it;

  // prefetch Kaug for first tile
  bf16x8 kn[8];
  {
    const short* kb = kbase + (size_t)(jt0 * 32 + li) * 2304;
    const short* kt = ktab + (size_t)(jt0 * 32 + li) * 64;
    #pragma unroll
    for (int s = 0; s < 4; s++) {
      kn[s]     = *(const bf16x8*)(kb + s * 16 + hi * 8);
      kn[4 + s] = *(const bf16x8*)(kt + s * 16 + hi * 8);
    }
  }

  for (int jt = jt0; jt <= jt1; ++jt) {
    const int J0 = jt * 32;
    bf16x8 kf[8];
    #pragma unroll
    for (int s = 0; s < 8; s++) kf[s] = kn[s];
    if (jt < jt1) {
      const short* kb = kbase + (size_t)((jt + 1) * 32 + li) * 2304;
      const short* kt = ktab + (size_t)((jt + 1) * 32 + li) * 64;
      #pragma unroll
      for (int s = 0; s < 4; s++) {
        kn[s]     = *(const bf16x8*)(kb + s * 16 + hi * 8);
        kn[4 + s] = *(const bf16x8*)(kt + s * 16 + hi * 8);
      }
    }
    // V loads issued early
    bf16x8 vc[4];
    #pragma unroll
    for (int s = 0; s < 2; s++) {
      vc[s * 2]     = *(const bf16x8*)(vbase + (size_t)li * 1024 + J0 + s * 16 + hi * 8);
      vc[s * 2 + 1] = *(const bf16x8*)(vbase + (size_t)(32 + li) * 1024 + J0 + s * 16 + hi * 8);
    }
    // --- S^T = Kaug . Qaug^T, two independent chains ---
    f32x16 sa0, sa1;
    #pragma unroll
    for (int r = 0; r < 16; r++) { sa0[r] = 0.0f; sa1[r] = 0.0f; }
    #pragma unroll
    for (int s = 0; s < 4; s++) {
      sa0 = __builtin_amdgcn_mfma_f32_32x32x16_bf16(kf[2 * s],     qf[2 * s],     sa0, 0, 0, 0);
      sa1 = __builtin_amdgcn_mfma_f32_32x32x16_bf16(kf[2 * s + 1], qf[2 * s + 1], sa1, 0, 0, 0);
    }
    // --- scale, mask, online softmax (lane owns row i = li) ---
    const int gi = I0 + li;
    float sv[16];
    float mx = -1e30f;
    #pragma unroll
    for (int r = 0; r < 16; r++) {
      const int j = (r & 3) + 8 * (r >> 2) + 4 * hi;
      float v = (sa0[r] + sa1[r]) * 0.125f;
      v = (J0 + j <= gi) ? v : -1e30f;
      sv[r] = v;
      mx = fmaxf(mx, v);
    }
    mx = fmaxf(mx, __shfl_xor(mx, 32));
    float mref = m_run;
    float alpha = 1.0f;
    const bool resc = !__all(mx <= m_run + 8.0f);  // defer-max (T13)
    if (resc) {
      mref = fmaxf(m_run, mx);
      alpha = __expf(m_run - mref);
      m_run = mref;
    }
    float psum = 0.0f;
    unsigned pw[8];
    #pragma unroll
    for (int t = 0; t < 8; t++) {
      const float p0 = __expf(sv[2 * t] - mref);
      const float p1 = __expf(sv[2 * t + 1] - mref);
      psum += p0 + p1;
      pw[t] = (unsigned)(unsigned short)f2bf(p0) |
              ((unsigned)(unsigned short)f2bf(p1) << 16);
    }
    psum += __shfl_xor(psum, 32);
    l_run = l_run * alpha + psum;
    if (resc) {
      #pragma unroll
      for (int r = 0; r < 16; r++) {
        const int row = (r & 3) + 8 * (r >> 2) + 4 * hi;
        const float a = __shfl(alpha, row);
        ya0[r] *= a;
        ya1[r] *= a;
      }
    }
    // --- PV: redistribute P via permlane32_swap, then MFMA ---
    #pragma unroll
    for (int s = 0; s < 2; s++) {
      unsigned a0 = pw[4 * s],     b0 = pw[4 * s + 2];
      unsigned a1 = pw[4 * s + 1], b1 = pw[4 * s + 3];
      asm volatile("v_permlane32_swap_b32 %0, %1" : "+v"(a0), "+v"(b0));
      asm volatile("v_permlane32_swap_b32 %0, %1" : "+v"(a1), "+v"(b1));
      u32x4 t4;
      t4[0] = a0; t4[1] = a1; t4[2] = b0; t4[3] = b1;
      const bf16x8 pf = __builtin_bit_cast(bf16x8, t4);
      ya0 = __builtin_amdgcn_mfma_f32_32x32x16_bf16(pf, vc[s * 2],     ya0, 0, 0, 0);
      ya1 = __builtin_amdgcn_mfma_f32_32x32x16_bf16(pf, vc[s * 2 + 1], ya1, 0, 0, 0);
    }
  }
  // --- write partials ---
  if (hi == 0) {
    mpart[(size_t)blk * 32 + li] = m_run;
    lpart[(size_t)blk * 32 + li] = l_run;
  }
  short* yb = Ypart + (size_t)blk * 2048;
  #pragma unroll
  for (int r = 0; r < 16; r++) {
    const int row = (r & 3) + 8 * (r >> 2) + 4 * hi;
    yb[row * 64 + li]      = f2bf(ya0[r]);
    yb[row * 64 + 32 + li] = f2bf(ya1[r]);
  }
}

// ---------------- attention combine: merge <=8 chunks ----------------
__global__ __launch_bounds__(256) void attn_combine(
    const float* __restrict__ mpart, const float* __restrict__ lpart,
    const short* __restrict__ Ypart, short* __restrict__ yout) {
  const int blk = blockIdx.x;  // bh*32 + it
  const int it = blk & 31, bh = blk >> 5;
  const int b = bh / 12, h = bh % 12;
  const int g = it >> 2;
  const int nc = g + 1;
  const int base = bh * 144 + 2 * g * (g + 1) + (it - g * 4) * (g + 1);
  const int row = threadIdx.x >> 3;
  const int c0 = (threadIdx.x & 7) * 8;
  float mv[8], lv[8], wgt[8];
  float m = -1e30f;
  #pragma unroll
  for (int cI = 0; cI < 8; ++cI) {
    mv[cI] = (cI < nc) ? mpart[(size_t)(base + cI) * 32 + row] : -1e30f;
    lv[cI] = (cI < nc) ? lpart[(size_t)(base + cI) * 32 + row] : 0.0f;
    m = fmaxf(m, mv[cI]);
  }
  float L = 0.0f;
  #pragma unroll
  for (int cI = 0; cI < 8; ++cI) {
    wgt[cI] = __expf(mv[cI] - m);
    L += lv[cI] * wgt[cI];
  }
  const float inv = 1.0f / L;
  float y[8];
  #pragma unroll
  for (int r = 0; r < 8; r++) y[r] = 0.0f;
  #pragma unroll
  for (int cI = 0; cI < 8; ++cI) {
    if (cI < nc) {
      bf16x8 v = *(const bf16x8*)(Ypart + ((size_t)(base + cI) * 32 + row) * 64 + c0);
      #pragma unroll
      for (int r = 0; r < 8; r++) y[r] += bf2f(v[r]) * wgt[cI];
    }
  }
  short* dst = yout + (size_t)(b * 1024 + it * 32 + row) * 768 + h * 64 + c0;
  #pragma unroll
  for (int r = 0; r < 8; r++) dst[r] = f2bf(y[r] * inv);
}

// ---------------- launch ----------------
extern "C" void kernel_launch(void* const* d_in, const int* in_sizes, int n_in,
                              void* d_out, int out_size, void* d_ws, size_t ws_size,
                              hipStream_t stream) {
  const float* x       = (const float*)d_in[0];
  const float* ln1_w   = (const float*)d_in[1];
  const float* w_attn  = (const float*)d_in[2];
  // d_in[3] = w_pos (dead code in reference)
  const float* w_cproj = (const float*)d_in[4];
  const float* ln2_w   = (const float*)d_in[5];
  const float* w_fc    = (const float*)d_in[6];
  const float* w_mproj = (const float*)d_in[7];
  float* out = (float*)d_out;
  char* ws = (char*)d_ws;

  short* wT_attn  = (short*)(ws + 0);          // [2304][768]
  short* wT_cproj = (short*)(ws + 3538944);    // [768][768]
  short* wT_fc    = (short*)(ws + 4718592);    // [3072][768]
  short* wT_mproj = (short*)(ws + 9437184);    // [768][3072]
  short* ktab     = (short*)(ws + 14155776);   // [1024][64] bf16 (128KB)
  short* h_bf     = (short*)(ws + 14417920);   // [4096][768]; reused as qpr
  short* qpr      = (short*)(ws + 14417920);   // [48*1024][64] (h_bf dead then)
  short* qkv_bf   = (short*)(ws + 20709376);   // [4096][2304]
  short* vT       = (short*)(ws + 39583744);   // [48][64][1024]
  short* y_att    = (short*)(ws + 45875200);   // [4096][768]
  short* h2_bf    = (short*)(ws + 52166656);   // [4096][768]
  short* hfc_bf   = (short*)(ws + 58458112);   // [4096][3072]
  // attention partials alias the (not-yet-live) MLP buffers:
  float* mpart = (float*)(ws + 52166656);      // [6912][32] f32
  float* lpart = (float*)(ws + 53051392);      // [6912][32] f32
  short* Ypart = (short*)(ws + 53936128);      // [6912][32][64] bf16
  // split-K partials (after hfc_bf): 4 x [4096][768] f32 = 48MB
  float* Cpart = (float*)(ws + 83623936);
  const bool use_splitk = ws_size >= 133955584ull;

  // weight prep
  wtrans_kernel<<<dim3(72, 24), 256, 0, stream>>>(w_attn, wT_attn, 768, 2304);
  wtrans_kernel<<<dim3(24, 24), 256, 0, stream>>>(w_cproj, wT_cproj, 768, 768);
  wtrans_kernel<<<dim3(96, 24), 256, 0, stream>>>(w_fc, wT_fc, 768, 3072);
  wtrans_kernel<<<dim3(24, 96), 256, 0, stream>>>(w_mproj, wT_mproj, 3072, 768);
  ktab_kernel<<<128, 256, 0, stream>>>(ktab);

  // attention branch
  ln_kernel<<<4096, 256, 0, stream>>>(x, ln1_w, h_bf);
  gemm_bt<0, 128, 128><<<dim3(18, 32), 256, 0, stream>>>(
      h_bf, wT_attn, nullptr, nullptr, qkv_bf, 4096, 2304, 768, 768, 768);
  qprime_kernel<<<6144, 256, 0, stream>>>(qkv_bf, qpr);
  vtrans_kernel<<<768, 256, 0, stream>>>(qkv_bf, vT);
  attn_part<<<6912, 64, 0, stream>>>(qkv_bf, vT, qpr, ktab, mpart, lpart, Ypart);
  attn_combine<<<1536, 256, 0, stream>>>(mpart, lpart, Ypart, y_att);
  gemm_bt<1, 64, 64><<<dim3(12, 64), 256, 0, stream>>>(
      y_att, wT_cproj, x, out, nullptr, 4096, 768, 768, 768, 768);
  // MLP branch
  ln_kernel<<<4096, 256, 0, stream>>>(out, ln2_w, h2_bf);
  gemm_bt<2, 128, 128><<<dim3(24, 32), 256, 0, stream>>>(
      h2_bf, wT_fc, nullptr, nullptr, hfc_bf, 4096, 3072, 768, 768, 768);
  if (use_splitk) {
    gemm_bt<3, 128, 128><<<dim3(6, 32, 4), 256, 0, stream>>>(
        hfc_bf, wT_mproj, nullptr, Cpart, nullptr, 4096, 768, 768, 3072, 3072);
    reduce_splitk<<<3072, 256, 0, stream>>>(Cpart, out, out);
  } else {
    gemm_bt<1, 64, 64><<<dim3(12, 64), 256, 0, stream>>>(
        hfc_bf, wT_mproj, out, out, nullptr, 4096, 768, 3072, 3072, 3072);
  }
}